// Round 4
// baseline (2161.598 us; speedup 1.0000x reference)
//
#include <hip/hip_runtime.h>

#define D_MODEL 4096
#define HID     10922
#define HIDP    11008   // padded to multiple of 256
#define MTOK    4096
#define QMAXF   127.0f

typedef _Float16 half8  __attribute__((ext_vector_type(8)));
typedef _Float16 half4v __attribute__((ext_vector_type(4)));
typedef float    floatx4 __attribute__((ext_vector_type(4)));

// ---------------- async global->LDS (16B per lane, wave-uniform LDS base) ----
__device__ __forceinline__ void gl_lds16(const void* g, void* l) {
  __builtin_amdgcn_global_load_lds((__attribute__((address_space(1))) void*)g,
                                   (__attribute__((address_space(3))) void*)l,
                                   16, 0, 0);
}

__device__ __forceinline__ float slot_scale(const unsigned* slots, int idx) {
  return fmaxf(__uint_as_float(slots[idx]) / QMAXF, 1e-8f);
}

// ---------------- absmax reduction ------------------------------------------
__global__ void absmax_k(const float* __restrict__ in, int n4, unsigned* __restrict__ slot) {
  int tid = blockIdx.x * blockDim.x + threadIdx.x;
  int stride = gridDim.x * blockDim.x;
  float m = 0.f;
  const float4* in4 = (const float4*)in;
  for (int i = tid; i < n4; i += stride) {
    float4 v = in4[i];
    m = fmaxf(m, fmaxf(fmaxf(fabsf(v.x), fabsf(v.y)), fmaxf(fabsf(v.z), fabsf(v.w))));
  }
  #pragma unroll
  for (int off = 32; off; off >>= 1) m = fmaxf(m, __shfl_down(m, off));
  __shared__ float sm[4];
  int lane = threadIdx.x & 63, w = threadIdx.x >> 6;
  if (!lane) sm[w] = m;
  __syncthreads();
  if (!threadIdx.x) {
    m = fmaxf(fmaxf(sm[0], sm[1]), fmaxf(sm[2], sm[3]));
    atomicMax(slot, __float_as_uint(m));  // non-negative floats: uint order == float order
  }
}

// ---------------- quantize fp32 -> fp16 int grid, with zero padding ---------
__global__ void quant_k(const float* __restrict__ in, _Float16* __restrict__ out,
                        int rows_in, int cols_in, int cols_out, int total8,
                        const unsigned* __restrict__ slot) {
  float s = fmaxf(__uint_as_float(*slot) / QMAXF, 1e-8f);
  int t = blockIdx.x * blockDim.x + threadIdx.x;
  if (t >= total8) return;
  int idx = t * 8;
  int r = idx / cols_out;
  int c = idx - r * cols_out;
  half8 h;
  if (r < rows_in && c + 8 <= cols_in) {
    const float2* p = (const float2*)(in + (size_t)r * cols_in + c);
    #pragma unroll
    for (int j = 0; j < 4; ++j) {
      float2 v = p[j];
      float q0 = fminf(fmaxf(rintf(v.x / s), -QMAXF), QMAXF);
      float q1 = fminf(fmaxf(rintf(v.y / s), -QMAXF), QMAXF);
      h[2 * j]     = (_Float16)q0;
      h[2 * j + 1] = (_Float16)q1;
    }
  } else {
    #pragma unroll
    for (int j = 0; j < 8; ++j) {
      int cc = c + j;
      float v = 0.f;
      if (r < rows_in && cc < cols_in) v = in[(size_t)r * cols_in + cc];
      float q = fminf(fmaxf(rintf(v / s), -QMAXF), QMAXF);
      h[j] = (_Float16)q;
    }
  }
  *(half8*)(out + idx) = h;
}

// ---------------- activation: silu(fq(gate)) * fq(up) -----------------------
__device__ __forceinline__ float act_val(float g, float u, float sg, float su) {
  float gq = fminf(fmaxf(rintf(g / sg), -QMAXF), QMAXF) * sg;
  float uq = fminf(fmaxf(rintf(u / su), -QMAXF), QMAXF) * su;
  float sig = (gq >= 0.f) ? (1.f / (1.f + expf(-gq)))
                          : (expf(gq) / (1.f + expf(gq)));
  return (gq * sig) * uq;
}

__global__ void act_max_k(const float* __restrict__ gate, const float* __restrict__ up,
                          const unsigned* __restrict__ slots, unsigned* __restrict__ outslot,
                          int n4) {
  float sg = slot_scale(slots, 4);
  float su = slot_scale(slots, 5);
  int tid = blockIdx.x * blockDim.x + threadIdx.x;
  int stride = gridDim.x * blockDim.x;
  float m = 0.f;
  const float4* g4 = (const float4*)gate;
  const float4* u4 = (const float4*)up;
  for (int i = tid; i < n4; i += stride) {
    float4 g = g4[i], u = u4[i];
    m = fmaxf(m, fabsf(act_val(g.x, u.x, sg, su)));
    m = fmaxf(m, fabsf(act_val(g.y, u.y, sg, su)));
    m = fmaxf(m, fabsf(act_val(g.z, u.z, sg, su)));
    m = fmaxf(m, fabsf(act_val(g.w, u.w, sg, su)));
  }
  #pragma unroll
  for (int off = 32; off; off >>= 1) m = fmaxf(m, __shfl_down(m, off));
  __shared__ float sm[4];
  int lane = threadIdx.x & 63, w = threadIdx.x >> 6;
  if (!lane) sm[w] = m;
  __syncthreads();
  if (!threadIdx.x) {
    m = fmaxf(fmaxf(sm[0], sm[1]), fmaxf(sm[2], sm[3]));
    atomicMax(outslot, __float_as_uint(m));
  }
}

__global__ void act_quant_k(const float* __restrict__ gate, const float* __restrict__ up,
                            const unsigned* __restrict__ slots, _Float16* __restrict__ actq,
                            int n4) {
  float sg = slot_scale(slots, 4);
  float su = slot_scale(slots, 5);
  float sa = slot_scale(slots, 6);
  int tid = blockIdx.x * blockDim.x + threadIdx.x;
  int stride = gridDim.x * blockDim.x;
  const float4* g4 = (const float4*)gate;
  const float4* u4 = (const float4*)up;
  for (int i = tid; i < n4; i += stride) {
    float4 g = g4[i], u = u4[i];
    float a0 = act_val(g.x, u.x, sg, su);
    float a1 = act_val(g.y, u.y, sg, su);
    float a2 = act_val(g.z, u.z, sg, su);
    float a3 = act_val(g.w, u.w, sg, su);
    half4v h;
    h[0] = (_Float16)fminf(fmaxf(rintf(a0 / sa), -QMAXF), QMAXF);
    h[1] = (_Float16)fminf(fmaxf(rintf(a1 / sa), -QMAXF), QMAXF);
    h[2] = (_Float16)fminf(fmaxf(rintf(a2 / sa), -QMAXF), QMAXF);
    h[3] = (_Float16)fminf(fmaxf(rintf(a3 / sa), -QMAXF), QMAXF);
    *(half4v*)(actq + (size_t)i * 4) = h;
  }
}

// ---------------- GEMM: 256x256 tile, BK=64, 8-phase counted-vmcnt schedule --
// C[m,n] = (sum_k A[m,k]*B[n,k]) * sA*sB + bias[n], absmax of C tracked.
// 8 waves (2M x 4N). Per-wave output footprint is INTERLEAVED across tile
// halves — rows {wrow*64..+63} u {128+wrow*64..+63}, cols {wcol*32..+31} u
// {128+wcol*32..+31} — so phase (HM,HN) reads EXACTLY A-half HM and B-half HN
// for ALL waves; half-tile liveness matches the staging slots (A0 dead after
// P2, B0 after P3, A1/B1 after P4).
// LDS: A,B each 2 buffers x 2 half-tiles of [128 rows][64 fp16] (128 B rows).
// Swizzle: logical 16B-chunk c of row r lives at LDS chunk c ^ (r&7); inverse
// permutation applied to the per-lane GLOBAL source address at staging time
// (global_load_lds dest must stay linear — both-sides rule).
// Schedule per steady iteration (K-tiles kt,kt+1; kt even->buf0):
//   P1 (0,0)buf0  stage kt+1.A1->b1    P5 (0,0)buf1  stage kt+2.A1->b0
//   P2 (0,1)buf0  stage kt+1.B1->b1    P6 (0,1)buf1  stage kt+2.B1->b0
//   P3 (1,0)buf0  stage kt+2.A0->b0    P7 (1,0)buf1  stage kt+3.A0->b1
//   P4 (1,1)buf0  stage kt+2.B0->b0    P8 (1,1)buf1  stage kt+3.B0->b1
//                 vmcnt(4) post-MFMA                 vmcnt(4) post-MFMA
// vmcnt(4) waits the oldest 8 of 12 in-flight = exactly the K-tile read next;
// the newest 4 stay in flight across the barrier. The wait sits AFTER the
// MFMA cluster (just before the closing barrier): each waited load gains a
// full MFMA region of flight time, and the "memory" clobber doubles as the
// fence that keeps next-phase ds_reads below it.
// Round-4 scheduling change (m141 lesson): NO sched_barrier around barriers
// except ONE sched_barrier(0) after each CLOSING barrier — required so
// next-phase ds_reads cannot hoist into the window between a wave's own
// vmcnt wait and the barrier (other waves' stages may not have landed yet).
// Everything else floats: the compiler may interleave ds_read issue with
// MFMA and emit fine-grained lgkmcnt waits.
// FINAL iteration is PEELED: stages only kt+1.A1/B1, drains vmcnt(0) at its
// P4 — no in-flight LDS-DMA at workgroup retirement.

#define NOOP ((void)0)
#define VM4() asm volatile("s_waitcnt vmcnt(4)" ::: "memory")
#define VM0() asm volatile("s_waitcnt vmcnt(0)" ::: "memory")

#define STAGE(GB, LS, LD, TB, KT, BUF, H) do {                                \
    const char* _s = (GB) + ((size_t)((TB) + (H) * 128 + s_r0) * (LD)         \
                             + (size_t)(KT) * 64) * 2 + s_cb;                 \
    char* _d = (char*)(LS) + ((BUF) * 2 + (H)) * 16384 + wave * 1024;         \
    gl_lds16(_s, _d);                                                         \
    gl_lds16(_s + (size_t)(LD) * 128, _d + 8192);                             \
  } while (0)

#define PHASE(BUF, HM, HN, STG, WT) do {                                      \
    half8 af[4][2], bf[2][2];                                                 \
    _Pragma("unroll")                                                         \
    for (int i2 = 0; i2 < 4; ++i2) {                                          \
      int gr = (HM) * 128 + wrow * 64 + i2 * 16 + l16;                        \
      const char* pa = (const char*)As + ((BUF) * 2 + (gr >> 7)) * 16384      \
                       + (gr & 127) * 128;                                    \
      _Pragma("unroll")                                                       \
      for (int ks = 0; ks < 2; ++ks)                                          \
        af[i2][ks] = *(const half8*)(pa + (((ks * 4 + quad) ^ (l16 & 7)) * 16)); \
    }                                                                         \
    _Pragma("unroll")                                                         \
    for (int j2 = 0; j2 < 2; ++j2) {                                          \
      int gc = (HN) * 128 + wcol * 32 + j2 * 16 + l16;                        \
      const char* pb = (const char*)Bs + ((BUF) * 2 + (gc >> 7)) * 16384      \
                       + (gc & 127) * 128;                                    \
      _Pragma("unroll")                                                       \
      for (int ks = 0; ks < 2; ++ks)                                          \
        bf[j2][ks] = *(const half8*)(pb + (((ks * 4 + quad) ^ (l16 & 7)) * 16)); \
    }                                                                         \
    STG;                                                                      \
    __builtin_amdgcn_s_barrier();                                             \
    __builtin_amdgcn_s_setprio(1);                                            \
    _Pragma("unroll")                                                         \
    for (int i2 = 0; i2 < 4; ++i2)                                            \
      _Pragma("unroll")                                                       \
      for (int j2 = 0; j2 < 2; ++j2)                                          \
        _Pragma("unroll")                                                     \
        for (int ks = 0; ks < 2; ++ks)                                        \
          acc[(HM) * 4 + i2][(HN) * 2 + j2] =                                 \
              __builtin_amdgcn_mfma_f32_16x16x32_f16(                         \
                  af[i2][ks], bf[j2][ks],                                     \
                  acc[(HM) * 4 + i2][(HN) * 2 + j2], 0, 0, 0);                \
    __builtin_amdgcn_s_setprio(0);                                            \
    WT;                                                                       \
    __builtin_amdgcn_s_barrier();                                             \
    __builtin_amdgcn_sched_barrier(0);                                        \
  } while (0)

__global__ __launch_bounds__(512, 2) void gemm_k(
    const _Float16* __restrict__ A, const _Float16* __restrict__ B,
    const float* __restrict__ bias, float* __restrict__ C,
    int K, int lda, int ldb, int ldc, int nbias,
    const unsigned* __restrict__ slots, int sa_idx, int sb_idx,
    unsigned* __restrict__ maxslot) {
  __shared__ __align__(16) _Float16 As[2 * 2 * 128 * 64];   // 64 KiB
  __shared__ __align__(16) _Float16 Bs[2 * 2 * 128 * 64];   // 64 KiB
  __shared__ float smx[8];

  const int tid = threadIdx.x;
  const int wave = tid >> 6, lane = tid & 63;
  const int wrow = wave >> 2, wcol = wave & 3;
  const int l16 = lane & 15, quad = lane >> 4;

  // XCD-aware bijective swizzle (T1). Both grids have nwg % 8 == 0
  // (688, 256) and gridDim.x == 16 (MTOK/256). Within an XCD chunk, M-tile
  // varies fastest, so all 16 blocks sharing one B-panel land on one XCD L2.
  const int nwg  = gridDim.x * gridDim.y;
  const int flat = blockIdx.y * gridDim.x + blockIdx.x;
  const int swz  = (flat & 7) * (nwg >> 3) + (flat >> 3);
  const int tm = (swz & 15) * 256;
  const int tn = (swz >> 4) * 256;

  // staging geometry: per gl_lds16 call a wave covers 8 rows x 8 chunks;
  // thread's row-in-half = wave*8 + (lane>>3) (+64 for second call),
  // source chunk pre-swizzled: (lane&7) ^ (row&7), row&7 == lane>>3.
  const int s_r0 = wave * 8 + (lane >> 3);
  const int s_cb = ((lane & 7) ^ (lane >> 3)) * 16;

  const char* Ab = (const char*)A;
  const char* Bb = (const char*)B;

  floatx4 acc[8][4] = {};

  const int NT = K >> 6;  // K-tiles of 64; K=4096 -> 64, K=11008 -> 172 (even)

  // prologue: kt0 fully, kt1 {A0,B0}; wait kt0 (keep kt1's 4 loads flying)
  STAGE(Ab, As, lda, tm, 0, 0, 0);
  STAGE(Ab, As, lda, tm, 0, 0, 1);
  STAGE(Bb, Bs, ldb, tn, 0, 0, 0);
  STAGE(Bb, Bs, ldb, tn, 0, 0, 1);
  STAGE(Ab, As, lda, tm, 1, 1, 0);
  STAGE(Bb, Bs, ldb, tn, 1, 1, 0);
  VM4();
  __builtin_amdgcn_s_barrier();
  __builtin_amdgcn_sched_barrier(0);   // no ds_read may sit between VM4 and barrier

  // steady iterations: all staged K-tile indices in-range, no clamping
  for (int kt = 0; kt + 2 < NT; kt += 2) {
    PHASE(0, 0, 0, STAGE(Ab, As, lda, tm, kt + 1, 1, 1), NOOP);
    PHASE(0, 0, 1, STAGE(Bb, Bs, ldb, tn, kt + 1, 1, 1), NOOP);
    PHASE(0, 1, 0, STAGE(Ab, As, lda, tm, kt + 2, 0, 0), NOOP);
    PHASE(0, 1, 1, STAGE(Bb, Bs, ldb, tn, kt + 2, 0, 0), VM4());
    PHASE(1, 0, 0, STAGE(Ab, As, lda, tm, kt + 2, 0, 1), NOOP);
    PHASE(1, 0, 1, STAGE(Bb, Bs, ldb, tn, kt + 2, 0, 1), NOOP);
    PHASE(1, 1, 0, STAGE(Ab, As, lda, tm, kt + 3, 1, 0), NOOP);
    PHASE(1, 1, 1, STAGE(Bb, Bs, ldb, tn, kt + 3, 1, 0), VM4());
  }

  // peeled final iteration (kt = NT-2): stage only kt+1.A1/B1; drain at P4.
  {
    const int kt = NT - 2;
    PHASE(0, 0, 0, STAGE(Ab, As, lda, tm, kt + 1, 1, 1), NOOP);
    PHASE(0, 0, 1, STAGE(Bb, Bs, ldb, tn, kt + 1, 1, 1), NOOP);
    PHASE(0, 1, 0, NOOP, NOOP);
    PHASE(0, 1, 1, NOOP, VM0());
    PHASE(1, 0, 0, NOOP, NOOP);
    PHASE(1, 0, 1, NOOP, NOOP);
    PHASE(1, 1, 0, NOOP, NOOP);
    PHASE(1, 1, 1, NOOP, NOOP);
  }
  VM0();  // insurance: nothing in flight at retirement

  // epilogue: scale + bias + store + block absmax
  // acc[i][j]: row = tm + (i>>2)*128 + wrow*64 + (i&3)*16 + quad*4 + r
  //            col = tn + (j>>1)*128 + wcol*32 + (j&1)*16 + l16
  float scale = slot_scale(slots, sa_idx) * slot_scale(slots, sb_idx);
  float mloc = 0.f;
  #pragma unroll
  for (int i = 0; i < 8; ++i) {
    int rg0 = tm + (i >> 2) * 128 + wrow * 64 + (i & 3) * 16 + quad * 4;
    #pragma unroll
    for (int j = 0; j < 4; ++j) {
      int cg = tn + (j >> 1) * 128 + wcol * 32 + (j & 1) * 16 + l16;
      float bv = (cg < nbias) ? bias[cg] : 0.f;  // padded cols: acc==0, bv==0 -> exact 0
      #pragma unroll
      for (int r = 0; r < 4; ++r) {
        float v = acc[i][j][r] * scale + bv;
        C[(size_t)(rg0 + r) * ldc + cg] = v;
        mloc = fmaxf(mloc, fabsf(v));
      }
    }
  }
  #pragma unroll
  for (int off = 32; off; off >>= 1) mloc = fmaxf(mloc, __shfl_down(mloc, off));
  if (!lane) smx[wave] = mloc;
  __syncthreads();
  if (!tid) {
    float m = smx[0];
    #pragma unroll
    for (int w = 1; w < 8; ++w) m = fmaxf(m, smx[w]);
    atomicMax(maxslot, __float_as_uint(m));
  }
}

// ---------------- host-side orchestration -----------------------------------
extern "C" void kernel_launch(void* const* d_in, const int* in_sizes, int n_in,
                              void* d_out, int out_size, void* d_ws, size_t ws_size,
                              hipStream_t stream) {
  const float* x  = (const float*)d_in[0];
  const float* wg = (const float*)d_in[1];
  const float* wu = (const float*)d_in[2];
  const float* wd = (const float*)d_in[3];
  const float* bg = (const float*)d_in[4];
  const float* bu = (const float*)d_in[5];
  const float* bd = (const float*)d_in[6];
  float* out = (float*)d_out;

  char* ws = (char*)d_ws;
  unsigned* slots = (unsigned*)ws;
  // slots: 0:max|x| 1:max|wg| 2:max|wu| 3:max|wd| 4:max|gate| 5:max|up| 6:max|act| 7:dummy
  const size_t XQ_B = (size_t)MTOK * D_MODEL * 2;   // 33,554,432
  const size_t WQ_B = (size_t)HIDP * D_MODEL * 2;   // 90,177,536
  const size_t GU_B = (size_t)MTOK * HIDP * 4;      // 180,355,072

  _Float16* xq   = (_Float16*)(ws + 256);
  _Float16* wgq  = (_Float16*)(ws + 256 + XQ_B);
  _Float16* wuq  = (_Float16*)(ws + 256 + XQ_B + WQ_B);
  float*    gate = (float*)   (ws + 256 + XQ_B + 2 * WQ_B);
  float*    up   = (float*)   (ws + 256 + XQ_B + 2 * WQ_B + GU_B);
  // reuse dead regions after GEMM1:
  _Float16* actq = wgq;                              // 4096*11008*2 == WQ_B
  _Float16* wdq  = wuq;                              // 4096*11008*2 == WQ_B

  hipMemsetAsync(ws, 0, 256, stream);  // zero the max slots

  // 1) absmax of inputs
  absmax_k<<<2048, 256, 0, stream>>>(x,  MTOK * D_MODEL / 4, slots + 0);
  absmax_k<<<2048, 256, 0, stream>>>(wg, HID * D_MODEL / 4,  slots + 1);
  absmax_k<<<2048, 256, 0, stream>>>(wu, HID * D_MODEL / 4,  slots + 2);
  absmax_k<<<2048, 256, 0, stream>>>(wd, MTOK * HID / 4,     slots + 3);

  // 2) quantize x, wg, wu to fp16 int grid (weights padded to HIDP rows)
  {
    int t8 = MTOK * D_MODEL / 8;
    quant_k<<<(t8 + 255) / 256, 256, 0, stream>>>(x, xq, MTOK, D_MODEL, D_MODEL, t8, slots + 0);
    int w8 = HIDP * D_MODEL / 8;
    quant_k<<<(w8 + 255) / 256, 256, 0, stream>>>(wg, wgq, HID, D_MODEL, D_MODEL, w8, slots + 1);
    quant_k<<<(w8 + 255) / 256, 256, 0, stream>>>(wu, wuq, HID, D_MODEL, D_MODEL, w8, slots + 2);
  }

  // 3) GEMM1: gate & up (fp32, scale+bias fused, absmax tracked)
  {
    dim3 g1(MTOK / 256, HIDP / 256);  // (16, 43) -> 688 blocks, %8==0
    gemm_k<<<g1, 512, 0, stream>>>(xq, wgq, bg, gate, D_MODEL, D_MODEL, D_MODEL, HIDP, HID,
                                   slots, 0, 1, slots + 4);
    gemm_k<<<g1, 512, 0, stream>>>(xq, wuq, bu, up,   D_MODEL, D_MODEL, D_MODEL, HIDP, HID,
                                   slots, 0, 2, slots + 5);
  }

  // 4) quantize wd into wuq region (cols padded to HIDP)
  {
    int t8 = MTOK * HIDP / 8;
    quant_k<<<(t8 + 255) / 256, 256, 0, stream>>>(wd, wdq, MTOK, HID, HIDP, t8, slots + 3);
  }

  // 5) activation: pass 1 (absmax), pass 2 (quantize into wgq region)
  {
    int n4 = MTOK * HIDP / 4;
    act_max_k<<<4096, 256, 0, stream>>>(gate, up, slots, slots + 6, n4);
    act_quant_k<<<4096, 256, 0, stream>>>(gate, up, slots, actq, n4);
  }

  // 6) GEMM2: out = actq . wdq^T * (sa*swd) + bd
  {
    dim3 g2(MTOK / 256, D_MODEL / 256);  // (16, 16) -> 256 blocks, %8==0
    gemm_k<<<g2, 512, 0, stream>>>(actq, wdq, bd, out, HIDP, HIDP, HIDP, D_MODEL, D_MODEL,
                                   slots, 6, 3, slots + 7);
  }
}

// Round 5
// 2039.199 us; speedup vs baseline: 1.0600x; 1.0600x over previous
//
#include <hip/hip_runtime.h>

#define D_MODEL 4096
#define HID     10922
#define HIDP    11008   // padded to multiple of 256
#define MTOK    4096
#define QMAXF   127.0f

typedef _Float16 half8  __attribute__((ext_vector_type(8)));
typedef _Float16 half4v __attribute__((ext_vector_type(4)));
typedef float    floatx4 __attribute__((ext_vector_type(4)));

// ---------------- async global->LDS (16B per lane, wave-uniform LDS base) ----
__device__ __forceinline__ void gl_lds16(const void* g, void* l) {
  __builtin_amdgcn_global_load_lds((__attribute__((address_space(1))) void*)g,
                                   (__attribute__((address_space(3))) void*)l,
                                   16, 0, 0);
}

__device__ __forceinline__ float slot_scale(const unsigned* slots, int idx) {
  return fmaxf(__uint_as_float(slots[idx]) / QMAXF, 1e-8f);
}

// ---------------- absmax reduction ------------------------------------------
__global__ void absmax_k(const float* __restrict__ in, int n4, unsigned* __restrict__ slot) {
  int tid = blockIdx.x * blockDim.x + threadIdx.x;
  int stride = gridDim.x * blockDim.x;
  float m = 0.f;
  const float4* in4 = (const float4*)in;
  for (int i = tid; i < n4; i += stride) {
    float4 v = in4[i];
    m = fmaxf(m, fmaxf(fmaxf(fabsf(v.x), fabsf(v.y)), fmaxf(fabsf(v.z), fabsf(v.w))));
  }
  #pragma unroll
  for (int off = 32; off; off >>= 1) m = fmaxf(m, __shfl_down(m, off));
  __shared__ float sm[4];
  int lane = threadIdx.x & 63, w = threadIdx.x >> 6;
  if (!lane) sm[w] = m;
  __syncthreads();
  if (!threadIdx.x) {
    m = fmaxf(fmaxf(sm[0], sm[1]), fmaxf(sm[2], sm[3]));
    atomicMax(slot, __float_as_uint(m));  // non-negative floats: uint order == float order
  }
}

// ---------------- quantize fp32 -> fp16 int grid, with zero padding ---------
__global__ void quant_k(const float* __restrict__ in, _Float16* __restrict__ out,
                        int rows_in, int cols_in, int cols_out, int total8,
                        const unsigned* __restrict__ slot) {
  float s = fmaxf(__uint_as_float(*slot) / QMAXF, 1e-8f);
  int t = blockIdx.x * blockDim.x + threadIdx.x;
  if (t >= total8) return;
  int idx = t * 8;
  int r = idx / cols_out;
  int c = idx - r * cols_out;
  half8 h;
  if (r < rows_in && c + 8 <= cols_in) {
    const float2* p = (const float2*)(in + (size_t)r * cols_in + c);
    #pragma unroll
    for (int j = 0; j < 4; ++j) {
      float2 v = p[j];
      float q0 = fminf(fmaxf(rintf(v.x / s), -QMAXF), QMAXF);
      float q1 = fminf(fmaxf(rintf(v.y / s), -QMAXF), QMAXF);
      h[2 * j]     = (_Float16)q0;
      h[2 * j + 1] = (_Float16)q1;
    }
  } else {
    #pragma unroll
    for (int j = 0; j < 8; ++j) {
      int cc = c + j;
      float v = 0.f;
      if (r < rows_in && cc < cols_in) v = in[(size_t)r * cols_in + cc];
      float q = fminf(fmaxf(rintf(v / s), -QMAXF), QMAXF);
      h[j] = (_Float16)q;
    }
  }
  *(half8*)(out + idx) = h;
}

// ---------------- activation: silu(fq(gate)) * fq(up) -----------------------
__device__ __forceinline__ float act_val(float g, float u, float sg, float su) {
  float gq = fminf(fmaxf(rintf(g / sg), -QMAXF), QMAXF) * sg;
  float uq = fminf(fmaxf(rintf(u / su), -QMAXF), QMAXF) * su;
  float sig = (gq >= 0.f) ? (1.f / (1.f + expf(-gq)))
                          : (expf(gq) / (1.f + expf(gq)));
  return (gq * sig) * uq;
}

__global__ void act_max_k(const float* __restrict__ gate, const float* __restrict__ up,
                          const unsigned* __restrict__ slots, unsigned* __restrict__ outslot,
                          int n4) {
  float sg = slot_scale(slots, 4);
  float su = slot_scale(slots, 5);
  int tid = blockIdx.x * blockDim.x + threadIdx.x;
  int stride = gridDim.x * blockDim.x;
  float m = 0.f;
  const float4* g4 = (const float4*)gate;
  const float4* u4 = (const float4*)up;
  for (int i = tid; i < n4; i += stride) {
    float4 g = g4[i], u = u4[i];
    m = fmaxf(m, fabsf(act_val(g.x, u.x, sg, su)));
    m = fmaxf(m, fabsf(act_val(g.y, u.y, sg, su)));
    m = fmaxf(m, fabsf(act_val(g.z, u.z, sg, su)));
    m = fmaxf(m, fabsf(act_val(g.w, u.w, sg, su)));
  }
  #pragma unroll
  for (int off = 32; off; off >>= 1) m = fmaxf(m, __shfl_down(m, off));
  __shared__ float sm[4];
  int lane = threadIdx.x & 63, w = threadIdx.x >> 6;
  if (!lane) sm[w] = m;
  __syncthreads();
  if (!threadIdx.x) {
    m = fmaxf(fmaxf(sm[0], sm[1]), fmaxf(sm[2], sm[3]));
    atomicMax(outslot, __float_as_uint(m));
  }
}

__global__ void act_quant_k(const float* __restrict__ gate, const float* __restrict__ up,
                            const unsigned* __restrict__ slots, _Float16* __restrict__ actq,
                            int n4) {
  float sg = slot_scale(slots, 4);
  float su = slot_scale(slots, 5);
  float sa = slot_scale(slots, 6);
  int tid = blockIdx.x * blockDim.x + threadIdx.x;
  int stride = gridDim.x * blockDim.x;
  const float4* g4 = (const float4*)gate;
  const float4* u4 = (const float4*)up;
  for (int i = tid; i < n4; i += stride) {
    float4 g = g4[i], u = u4[i];
    float a0 = act_val(g.x, u.x, sg, su);
    float a1 = act_val(g.y, u.y, sg, su);
    float a2 = act_val(g.z, u.z, sg, su);
    float a3 = act_val(g.w, u.w, sg, su);
    half4v h;
    h[0] = (_Float16)fminf(fmaxf(rintf(a0 / sa), -QMAXF), QMAXF);
    h[1] = (_Float16)fminf(fmaxf(rintf(a1 / sa), -QMAXF), QMAXF);
    h[2] = (_Float16)fminf(fmaxf(rintf(a2 / sa), -QMAXF), QMAXF);
    h[3] = (_Float16)fminf(fmaxf(rintf(a3 / sa), -QMAXF), QMAXF);
    *(half4v*)(actq + (size_t)i * 4) = h;
  }
}

// ---------------- GEMM: 256x256 tile, BK=64, 4-phase schedule ---------------
// C[m,n] = (sum_k A[m,k]*B[n,k]) * sA*sB + bias[n], absmax of C tracked.
// 8 waves (2M x 4N); per-wave output interleaved across tile halves:
// rows {wrow*64..} u {128+wrow*64..}, cols {wcol*32..} u {128+wcol*32..}.
// ROUND-5 RESTRUCTURE: 4 fat phases per 2 K-tiles (was 8). Phase = one
// (K-tile, A-half) over the FULL N: 32 MFMA/phase/wave. bf (all 4 B-frags,
// both B-halves) is loaded ONCE per K-tile and retained in registers across
// the phase pair — halves ds_read traffic (96 -> 48 b128 per 2 K-tiles per
// wave) and halves barrier count. Phase reads: A:16, B:8, C:16, D:8.
// LDS: A,B each 2 buffers x 2 half-tiles of [128 rows][64 fp16] (128 B rows).
// Chunk swizzle c ^= (r&7) with inverse applied to the global source address
// (global_load_lds dest stays linear — both-sides rule). Conflict-free
// (measured 0).
// Schedule per steady iteration (K-tiles kt->buf0, kt+1->buf1):
//   A: bf<-buf0.B, af<-buf0.A0; stage kt+1.{A1,B0,B1}->b1; BAR MFMA(rows0-3) BAR
//   B: af<-buf0.A1;             stage kt+2.A0->b0;         BAR MFMA(rows4-7) VM2 BAR
//   C: bf<-buf1.B, af<-buf1.A0; stage kt+2.{A1,B0,B1}->b0; BAR MFMA(rows0-3) BAR
//   D: af<-buf1.A1;             stage kt+3.A0->b1;         BAR MFMA(rows4-7) VM2 BAR
// Liveness: buf0.A0 dead after A, buf0.{A1,B0,B1} after B, buf1.A0 after C,
// buf1.{A1,B0,B1} after D — every stage target is dead with a barrier between.
// vmcnt(2) at end of B: outstanding = A's 6 + B's 2; waits A's stages (read
// at C/D). vmcnt(2) at end of D: waits C's stages (read at next A/B). B's
// reads (buf0.A1 <- prev C) and D's reads (buf1.A1 <- A) are covered by the
// preceding vmcnt+barrier. Prologue leaves exactly the steady-state 2 loads
// (kt+1.A0) in flight. FINAL iteration peeled: stages only kt+1.{A1,B0,B1},
// drains vmcnt(0) at its B — nothing in flight at retirement.

#define VM2() asm volatile("s_waitcnt vmcnt(2)" ::: "memory")
#define VM0() asm volatile("s_waitcnt vmcnt(0)" ::: "memory")
#define BAR() __builtin_amdgcn_s_barrier()
#define SCHED0() __builtin_amdgcn_sched_barrier(0)

#define STAGE(GB, LS, LD, TB, KT, BUF, H) do {                                \
    const char* _s = (GB) + ((size_t)((TB) + (H) * 128 + s_r0) * (LD)         \
                             + (size_t)(KT) * 64) * 2 + s_cb;                 \
    char* _d = (char*)(LS) + ((BUF) * 2 + (H)) * 16384 + wave * 1024;         \
    gl_lds16(_s, _d);                                                         \
    gl_lds16(_s + (size_t)(LD) * 128, _d + 8192);                             \
  } while (0)

// load all 4 B-fragments (both halves) from buffer BUF into bf[4][2]
#define LOAD_BF(BUF) do {                                                     \
    _Pragma("unroll")                                                         \
    for (int j2 = 0; j2 < 4; ++j2) {                                          \
      int gc = (j2 >> 1) * 128 + wcol * 32 + (j2 & 1) * 16 + l16;             \
      const char* pb = (const char*)Bs + ((BUF) * 2 + (gc >> 7)) * 16384      \
                       + (gc & 127) * 128;                                    \
      _Pragma("unroll")                                                       \
      for (int ks = 0; ks < 2; ++ks)                                          \
        bf[j2][ks] = *(const half8*)(pb + (((ks * 4 + quad) ^ (l16 & 7)) * 16)); \
    }                                                                         \
  } while (0)

// load the 4 A-fragments of half HM from buffer BUF into af[4][2]
#define LOAD_AF(BUF, HM) do {                                                 \
    _Pragma("unroll")                                                         \
    for (int i2 = 0; i2 < 4; ++i2) {                                          \
      int gr = (HM) * 128 + wrow * 64 + i2 * 16 + l16;                        \
      const char* pa = (const char*)As + ((BUF) * 2 + (gr >> 7)) * 16384      \
                       + (gr & 127) * 128;                                    \
      _Pragma("unroll")                                                       \
      for (int ks = 0; ks < 2; ++ks)                                          \
        af[i2][ks] = *(const half8*)(pa + (((ks * 4 + quad) ^ (l16 & 7)) * 16)); \
    }                                                                         \
  } while (0)

// 32 MFMA: acc rows HM*4..HM*4+3, all 4 col-frags, K=64
#define MFMA32(HM) do {                                                       \
    __builtin_amdgcn_s_setprio(1);                                            \
    _Pragma("unroll")                                                         \
    for (int i2 = 0; i2 < 4; ++i2)                                            \
      _Pragma("unroll")                                                       \
      for (int j2 = 0; j2 < 4; ++j2)                                          \
        _Pragma("unroll")                                                     \
        for (int ks = 0; ks < 2; ++ks)                                        \
          acc[(HM) * 4 + i2][j2] = __builtin_amdgcn_mfma_f32_16x16x32_f16(    \
              af[i2][ks], bf[j2][ks], acc[(HM) * 4 + i2][j2], 0, 0, 0);       \
    __builtin_amdgcn_s_setprio(0);                                            \
  } while (0)

__global__ __launch_bounds__(512, 2) void gemm_k(
    const _Float16* __restrict__ A, const _Float16* __restrict__ B,
    const float* __restrict__ bias, float* __restrict__ C,
    int K, int lda, int ldb, int ldc, int nbias,
    const unsigned* __restrict__ slots, int sa_idx, int sb_idx,
    unsigned* __restrict__ maxslot) {
  __shared__ __align__(16) _Float16 As[2 * 2 * 128 * 64];   // 64 KiB
  __shared__ __align__(16) _Float16 Bs[2 * 2 * 128 * 64];   // 64 KiB
  __shared__ float smx[8];

  const int tid = threadIdx.x;
  const int wave = tid >> 6, lane = tid & 63;
  const int wrow = wave >> 2, wcol = wave & 3;
  const int l16 = lane & 15, quad = lane >> 4;
  const int tm = blockIdx.x * 256, tn = blockIdx.y * 256;

  // staging geometry: per gl_lds16 call a wave covers 8 rows x 8 chunks;
  // thread's row-in-half = wave*8 + (lane>>3) (+64 for second call),
  // source chunk pre-swizzled: (lane&7) ^ (row&7), row&7 == lane>>3.
  const int s_r0 = wave * 8 + (lane >> 3);
  const int s_cb = ((lane & 7) ^ (lane >> 3)) * 16;

  const char* Ab = (const char*)A;
  const char* Bb = (const char*)B;

  floatx4 acc[8][4] = {};
  half8 bf[4][2];   // retained across each phase pair

  const int NT = K >> 6;  // K-tiles of 64; K=4096 -> 64, K=11008 -> 172 (even)

  // prologue: kt0 {A0,B0,B1,A1}->buf0, kt1.A0->buf1 (10 loads);
  // vmcnt(2): kt0 fully landed, kt1.A0 (2 loads) stays in flight ==
  // steady-state A-entry invariant.
  STAGE(Ab, As, lda, tm, 0, 0, 0);
  STAGE(Bb, Bs, ldb, tn, 0, 0, 0);
  STAGE(Bb, Bs, ldb, tn, 0, 0, 1);
  STAGE(Ab, As, lda, tm, 0, 0, 1);
  STAGE(Ab, As, lda, tm, 1, 1, 0);
  VM2();
  BAR();
  SCHED0();

  for (int kt = 0; kt + 2 < NT; kt += 2) {
    {  // Phase A: (kt, HM=0)
      half8 af[4][2];
      LOAD_BF(0);
      LOAD_AF(0, 0);
      STAGE(Ab, As, lda, tm, kt + 1, 1, 1);
      STAGE(Bb, Bs, ldb, tn, kt + 1, 1, 0);
      STAGE(Bb, Bs, ldb, tn, kt + 1, 1, 1);
      BAR();
      MFMA32(0);
      BAR(); SCHED0();
    }
    {  // Phase B: (kt, HM=1); bf retained
      half8 af[4][2];
      LOAD_AF(0, 1);
      STAGE(Ab, As, lda, tm, kt + 2, 0, 0);
      BAR();
      MFMA32(1);
      VM2();
      BAR(); SCHED0();
    }
    {  // Phase C: (kt+1, HM=0)
      half8 af[4][2];
      LOAD_BF(1);
      LOAD_AF(1, 0);
      STAGE(Ab, As, lda, tm, kt + 2, 0, 1);
      STAGE(Bb, Bs, ldb, tn, kt + 2, 0, 0);
      STAGE(Bb, Bs, ldb, tn, kt + 2, 0, 1);
      BAR();
      MFMA32(0);
      BAR(); SCHED0();
    }
    {  // Phase D: (kt+1, HM=1); bf retained
      half8 af[4][2];
      LOAD_AF(1, 1);
      STAGE(Ab, As, lda, tm, kt + 3, 1, 0);
      BAR();
      MFMA32(1);
      VM2();
      BAR(); SCHED0();
    }
  }

  {  // peeled final iteration (kt = NT-2): stage only kt+1.{A1,B0,B1}
    const int kt = NT - 2;
    {  // A
      half8 af[4][2];
      LOAD_BF(0);
      LOAD_AF(0, 0);
      STAGE(Ab, As, lda, tm, kt + 1, 1, 1);
      STAGE(Bb, Bs, ldb, tn, kt + 1, 1, 0);
      STAGE(Bb, Bs, ldb, tn, kt + 1, 1, 1);
      BAR();
      MFMA32(0);
      BAR(); SCHED0();
    }
    {  // B: drain everything (A's 6 + prologue leftovers)
      half8 af[4][2];
      LOAD_AF(0, 1);
      BAR();
      MFMA32(1);
      VM0();
      BAR(); SCHED0();
    }
    {  // C
      half8 af[4][2];
      LOAD_BF(1);
      LOAD_AF(1, 0);
      BAR();
      MFMA32(0);
      BAR(); SCHED0();
    }
    {  // D
      half8 af[4][2];
      LOAD_AF(1, 1);
      BAR();
      MFMA32(1);
      BAR(); SCHED0();
    }
  }
  VM0();  // insurance: nothing in flight at retirement

  // epilogue: scale + bias + store + block absmax
  // acc[i][j]: row = tm + (i>>2)*128 + wrow*64 + (i&3)*16 + quad*4 + r
  //            col = tn + (j>>1)*128 + wcol*32 + (j&1)*16 + l16
  float scale = slot_scale(slots, sa_idx) * slot_scale(slots, sb_idx);
  float mloc = 0.f;
  #pragma unroll
  for (int i = 0; i < 8; ++i) {
    int rg0 = tm + (i >> 2) * 128 + wrow * 64 + (i & 3) * 16 + quad * 4;
    #pragma unroll
    for (int j = 0; j < 4; ++j) {
      int cg = tn + (j >> 1) * 128 + wcol * 32 + (j & 1) * 16 + l16;
      float bv = (cg < nbias) ? bias[cg] : 0.f;  // padded cols: acc==0, bv==0 -> exact 0
      #pragma unroll
      for (int r = 0; r < 4; ++r) {
        float v = acc[i][j][r] * scale + bv;
        C[(size_t)(rg0 + r) * ldc + cg] = v;
        mloc = fmaxf(mloc, fabsf(v));
      }
    }
  }
  #pragma unroll
  for (int off = 32; off; off >>= 1) mloc = fmaxf(mloc, __shfl_down(mloc, off));
  if (!lane) smx[wave] = mloc;
  __syncthreads();
  if (!tid) {
    float m = smx[0];
    #pragma unroll
    for (int w = 1; w < 8; ++w) m = fmaxf(m, smx[w]);
    atomicMax(maxslot, __float_as_uint(m));
  }
}

// ---------------- host-side orchestration -----------------------------------
extern "C" void kernel_launch(void* const* d_in, const int* in_sizes, int n_in,
                              void* d_out, int out_size, void* d_ws, size_t ws_size,
                              hipStream_t stream) {
  const float* x  = (const float*)d_in[0];
  const float* wg = (const float*)d_in[1];
  const float* wu = (const float*)d_in[2];
  const float* wd = (const float*)d_in[3];
  const float* bg = (const float*)d_in[4];
  const float* bu = (const float*)d_in[5];
  const float* bd = (const float*)d_in[6];
  float* out = (float*)d_out;

  char* ws = (char*)d_ws;
  unsigned* slots = (unsigned*)ws;
  // slots: 0:max|x| 1:max|wg| 2:max|wu| 3:max|wd| 4:max|gate| 5:max|up| 6:max|act| 7:dummy
  const size_t XQ_B = (size_t)MTOK * D_MODEL * 2;   // 33,554,432
  const size_t WQ_B = (size_t)HIDP * D_MODEL * 2;   // 90,177,536
  const size_t GU_B = (size_t)MTOK * HIDP * 4;      // 180,355,072

  _Float16* xq   = (_Float16*)(ws + 256);
  _Float16* wgq  = (_Float16*)(ws + 256 + XQ_B);
  _Float16* wuq  = (_Float16*)(ws + 256 + XQ_B + WQ_B);
  float*    gate = (float*)   (ws + 256 + XQ_B + 2 * WQ_B);
  float*    up   = (float*)   (ws + 256 + XQ_B + 2 * WQ_B + GU_B);
  // reuse dead regions after GEMM1:
  _Float16* actq = wgq;                              // 4096*11008*2 == WQ_B
  _Float16* wdq  = wuq;                              // 4096*11008*2 == WQ_B

  hipMemsetAsync(ws, 0, 256, stream);  // zero the max slots

  // 1) absmax of inputs
  absmax_k<<<2048, 256, 0, stream>>>(x,  MTOK * D_MODEL / 4, slots + 0);
  absmax_k<<<2048, 256, 0, stream>>>(wg, HID * D_MODEL / 4,  slots + 1);
  absmax_k<<<2048, 256, 0, stream>>>(wu, HID * D_MODEL / 4,  slots + 2);
  absmax_k<<<2048, 256, 0, stream>>>(wd, MTOK * HID / 4,     slots + 3);

  // 2) quantize x, wg, wu to fp16 int grid (weights padded to HIDP rows)
  {
    int t8 = MTOK * D_MODEL / 8;
    quant_k<<<(t8 + 255) / 256, 256, 0, stream>>>(x, xq, MTOK, D_MODEL, D_MODEL, t8, slots + 0);
    int w8 = HIDP * D_MODEL / 8;
    quant_k<<<(w8 + 255) / 256, 256, 0, stream>>>(wg, wgq, HID, D_MODEL, D_MODEL, w8, slots + 1);
    quant_k<<<(w8 + 255) / 256, 256, 0, stream>>>(wu, wuq, HID, D_MODEL, D_MODEL, w8, slots + 2);
  }

  // 3) GEMM1: gate & up (fp32, scale+bias fused, absmax tracked)
  {
    dim3 g1(MTOK / 256, HIDP / 256);  // (16, 43)
    gemm_k<<<g1, 512, 0, stream>>>(xq, wgq, bg, gate, D_MODEL, D_MODEL, D_MODEL, HIDP, HID,
                                   slots, 0, 1, slots + 4);
    gemm_k<<<g1, 512, 0, stream>>>(xq, wuq, bu, up,   D_MODEL, D_MODEL, D_MODEL, HIDP, HID,
                                   slots, 0, 2, slots + 5);
  }

  // 4) quantize wd into wuq region (cols padded to HIDP)
  {
    int t8 = MTOK * HIDP / 8;
    quant_k<<<(t8 + 255) / 256, 256, 0, stream>>>(wd, wdq, MTOK, HID, HIDP, t8, slots + 3);
  }

  // 5) activation: pass 1 (absmax), pass 2 (quantize into wgq region)
  {
    int n4 = MTOK * HIDP / 4;
    act_max_k<<<4096, 256, 0, stream>>>(gate, up, slots, slots + 6, n4);
    act_quant_k<<<4096, 256, 0, stream>>>(gate, up, slots, actq, n4);
  }

  // 6) GEMM2: out = actq . wdq^T * (sa*swd) + bd
  {
    dim3 g2(MTOK / 256, D_MODEL / 256);  // (16, 16)
    gemm_k<<<g2, 512, 0, stream>>>(actq, wdq, bd, out, HIDP, HIDP, HIDP, D_MODEL, D_MODEL,
                                   slots, 6, 3, slots + 7);
  }
}